// Round 9
// baseline (186.970 us; speedup 1.0000x reference)
//
#include <hip/hip_runtime.h>

#define DEVI __device__ __forceinline__

typedef __bf16 bf16x8 __attribute__((ext_vector_type(8)));
typedef float  f32x4  __attribute__((ext_vector_type(4)));
typedef float  f32x16 __attribute__((ext_vector_type(16)));
typedef unsigned int u32x4 __attribute__((ext_vector_type(4)));
typedef unsigned short u16;

// ---------- helpers ----------
static DEVI u16 f2bf(float f){                 // fp32 -> bf16 RNE
  unsigned u = __builtin_bit_cast(unsigned, f);
  u += 0x7fffu + ((u >> 16) & 1u);
  return (u16)(u >> 16);
}

static DEVI unsigned packbf(float a, float b){ // two fp32 -> packed bf16x2
  return (unsigned)f2bf(a) | ((unsigned)f2bf(b) << 16);
}

static DEVI f32x4 mfma16(bf16x8 a, bf16x8 b, f32x4 c){
  return __builtin_amdgcn_mfma_f32_16x16x32_bf16(a, b, c, 0, 0, 0);
}

static DEVI f32x16 mfma32(bf16x8 a, bf16x8 b, f32x16 c){
  return __builtin_amdgcn_mfma_f32_32x32x16_bf16(a, b, c, 0, 0, 0);
}

static DEVI void gload_lds16(const void* g, void* l){
  __builtin_amdgcn_global_load_lds((const __attribute__((address_space(1))) unsigned int*)g,
                                   (__attribute__((address_space(3))) unsigned int*)l,
                                   16, 0, 0);
}

// ---------- 1) fp32 -> bf16 conversion of x, Wqkv, Wout ----------
__global__ void convert_kernel(const float* __restrict__ x, const float* __restrict__ wq,
                               const float* __restrict__ wo,
                               u16* __restrict__ xb, u16* __restrict__ wqb, u16* __restrict__ wob){
  const int NX = 2048*1024, NQ = 3072*1024, NW = 1024*1024;
  const int total4 = (NX + NQ + NW) / 4;
  for (int i = blockIdx.x*blockDim.x + threadIdx.x; i < total4; i += gridDim.x*blockDim.x){
    int e = i * 4;
    const float* src; u16* dst; int off;
    if (e < NX)           { src = x;  dst = xb;  off = e; }
    else if (e < NX + NQ) { src = wq; dst = wqb; off = e - NX; }
    else                  { src = wo; dst = wob; off = e - NX - NQ; }
    float4 v = *(const float4*)(src + off);
    ushort4 o;
    o.x = f2bf(v.x); o.y = f2bf(v.y); o.z = f2bf(v.z); o.w = f2bf(v.w);
    *(ushort4*)(dst + off) = o;
  }
}

// ---------- 2/5) GEMM  C[M,N] = A[M,K] * B[N,K]^T  (bf16 in, fp32 acc) ----------
template<int EPI>
__global__ __launch_bounds__(512, 1)
void gemm_bt(const u16* __restrict__ A, const u16* __restrict__ B, int K,
             float* __restrict__ C, int ldc,
             u16* __restrict__ v_t, float* __restrict__ qkf){
  __shared__ u16 As[128*64];
  __shared__ u16 Bs[128*64];
  const int tid  = threadIdx.x;
  const int lane = tid & 63;
  const int wid  = tid >> 6;
  const int wr   = wid >> 2, wc = wid & 3;      // wave -> 64x32 sub-tile
  const int l15  = lane & 15, lg = lane >> 4;
  const int bm   = blockIdx.y * 128, bn = blockIdx.x * 128;

  const int c0 = tid, c1 = tid + 512;
  const int r0 = c0 >> 3, r1 = c1 >> 3;
  const int gb0 = ((c0 & 7) << 4) ^ ((r0 & 7) << 4);
  const int gb1 = ((c1 & 7) << 4) ^ ((r1 & 7) << 4);
  const u16* Ag0 = A + (size_t)(bm + r0) * K + (gb0 >> 1);
  const u16* Ag1 = A + (size_t)(bm + r1) * K + (gb1 >> 1);
  const u16* Bg0 = B + (size_t)(bn + r0) * K + (gb0 >> 1);
  const u16* Bg1 = B + (size_t)(bn + r1) * K + (gb1 >> 1);

  int baseA[4], swzA[4], baseB[2], swzB[2];
  #pragma unroll
  for (int m = 0; m < 4; ++m){
    int r = wr*64 + m*16 + l15;
    baseA[m] = r * 128; swzA[m] = (r & 7) << 4;
  }
  #pragma unroll
  for (int n = 0; n < 2; ++n){
    int r = wc*32 + n*16 + l15;
    baseB[n] = r * 128; swzB[n] = (r & 7) << 4;
  }
  const int colb = lg * 16;

  f32x4 acc[4][2] = {};
  const char* Ab = (const char*)As;
  const char* Bb = (const char*)Bs;

  for (int kb = 0; kb < K; kb += 64){
    gload_lds16(Ag0 + kb, &As[c0 * 8]);
    gload_lds16(Ag1 + kb, &As[c1 * 8]);
    gload_lds16(Bg0 + kb, &Bs[c0 * 8]);
    gload_lds16(Bg1 + kb, &Bs[c1 * 8]);
    __syncthreads();
    #pragma unroll
    for (int kk = 0; kk < 2; ++kk){
      bf16x8 av[4], bv[2];
      #pragma unroll
      for (int m = 0; m < 4; ++m)
        av[m] = *(const bf16x8*)(Ab + baseA[m] + ((kk*64 + colb) ^ swzA[m]));
      #pragma unroll
      for (int n = 0; n < 2; ++n)
        bv[n] = *(const bf16x8*)(Bb + baseB[n] + ((kk*64 + colb) ^ swzB[n]));
      #pragma unroll
      for (int m = 0; m < 4; ++m)
        #pragma unroll
        for (int n = 0; n < 2; ++n)
          acc[m][n] = mfma16(av[m], bv[n], acc[m][n]);
    }
    __syncthreads();
  }

  #pragma unroll
  for (int m = 0; m < 4; ++m){
    const int srow = bm + wr*64 + m*16 + lg*4;
    #pragma unroll
    for (int n = 0; n < 2; ++n){
      const int f = bn + wc*32 + n*16 + l15;
      f32x4 v = acc[m][n];
      if (EPI == 0){
        #pragma unroll
        for (int r = 0; r < 4; ++r)
          C[(size_t)(srow + r)*ldc + f] = v[r];
      } else {
        const int which = f >> 10, rem = f & 1023;
        const int h = rem >> 6, d = rem & 63;
        if (which == 2){
          ushort4 p;
          p.x = f2bf(v[0]); p.y = f2bf(v[1]); p.z = f2bf(v[2]); p.w = f2bf(v[3]);
          *(ushort4*)(v_t + ((size_t)(h*64 + d))*2048 + srow) = p;
        } else {
          float* dst = qkf + (((size_t)(which*16 + h))*2048 + srow)*64 + d;
          #pragma unroll
          for (int r = 0; r < 4; ++r) dst[(size_t)r * 64] = v[r];
        }
      }
    }
  }
}

// ---------- 3) RoPE on q,k (fp32 in, bf16 out) ----------
__global__ void rope_kernel(const float* __restrict__ qkf,
                            u16* __restrict__ q_r, u16* __restrict__ k_r){
  const int t = blockIdx.x*blockDim.x + threadIdx.x;   // 2^21 threads exactly
  const int i = t & 31;
  const int s = (t >> 5) & 2047;
  const int h = (t >> 16) & 15;
  const int w = t >> 20;
  const float2 xv = *(const float2*)(qkf + (((size_t)w*16 + h)*2048 + s)*64 + 2*i);
  const int idx0 = (2*i) & 31;
  const float NEGL = -0.41524101186091903f;            // -log2(10000)/32
  const float f0 = exp2f(NEGL * (float)idx0);
  const float f1 = exp2f(NEGL * (float)(idx0 + 1));
  const float a0 = (float)s * f0, a1 = (float)s * f1;
  float s0, c0, s1, c1;
  sincosf(a0, &s0, &c0);
  sincosf(a1, &s1, &c1);
  const float o0 = xv.x * c0 - xv.y * s0;
  const float o1 = xv.y * c1 + xv.x * s1;
  u16* dst = (w == 0 ? q_r : k_r) + ((size_t)h*2048 + s)*64 + 2*i;
  ushort2 pr; pr.x = f2bf(o0); pr.y = f2bf(o1);
  *(ushort2*)dst = pr;
}

// ---------- 4) causal flash attention v3 ----------
// 1 wave/block, 32 q-rows/wave, KB=32, 32x32x16 MFMA with SWAPPED operands:
//   S^T = mfma(K_frag, Q_frag)  -> lane owns q-col (lane&31) + 16 of 32 keys
//   softmax fully in-lane (15 fmax + one shfl_xor(32) per tile)
//   P^T packed to bf16 in regs, half-exchanged via shfl_xor(32) -> PV B-operand
//   O^T = mfma(V^T_frag, P^T_frag); V^T read from v_t[h][d][s] (contiguous)
// No LDS, no barriers. K/V straight from global (XCD-pinned -> L2-resident).
// Register double-buffer prefetch of next tile's K/V.
__global__ __launch_bounds__(64)
void attn_kernel(const u16* __restrict__ q_r, const u16* __restrict__ k_r,
                 const u16* __restrict__ v_t, u16* __restrict__ ao){
  const int lane = threadIdx.x & 63;
  const int l31 = lane & 31, hi = lane >> 5;
  const int bid = blockIdx.x;
  const int xcd = bid & 7, j = bid >> 3;       // 8 XCDs round-robin
  const int h   = xcd + ((j >= 64) ? 8 : 0);   // one hot head per XCD
  const int t   = 63 - (j & 63);               // longest tiles first
  const int q0  = t * 32;
  const int nt  = t + 1;                       // 32-key tiles
  const int q   = q0 + l31;                    // this lane's q-row

  // fragment base pointers (hi*8 = this half's k-slice offset)
  const u16* qgb = q_r + ((size_t)h*2048 + q)*64 + hi*8;
  const u16* kgb = k_r + ((size_t)h*2048 + l31)*64 + hi*8;
  const u16* vgb = v_t + ((size_t)h*64 + l31)*2048 + hi*8;

  // Q fragments (persistent): B-operand, col=q, k-slices d0=16*i
  bf16x8 qf0 = *(const bf16x8*)(qgb +  0);
  bf16x8 qf1 = *(const bf16x8*)(qgb + 16);
  bf16x8 qf2 = *(const bf16x8*)(qgb + 32);
  bf16x8 qf3 = *(const bf16x8*)(qgb + 48);

  f32x16 oc0 = {}, oc1 = {};
  float m = -3.0e38f, l = 0.f;

  // current-tile K/V fragments (tile 0)
  bf16x8 k0 = *(const bf16x8*)(kgb +  0);
  bf16x8 k1 = *(const bf16x8*)(kgb + 16);
  bf16x8 k2 = *(const bf16x8*)(kgb + 32);
  bf16x8 k3 = *(const bf16x8*)(kgb + 48);
  bf16x8 v00 = *(const bf16x8*)(vgb + 0);             // dt=0, kt=0
  bf16x8 v01 = *(const bf16x8*)(vgb + 16);            // dt=0, kt=1
  bf16x8 v10 = *(const bf16x8*)(vgb + 32*2048 + 0);   // dt=1, kt=0
  bf16x8 v11 = *(const bf16x8*)(vgb + 32*2048 + 16);  // dt=1, kt=1

  for (int ib = 0; ib < nt; ++ib){
    const int kb  = ib * 32;
    const int kbn = (ib + 1 < nt) ? kb + 32 : kb;     // clamped prefetch

    // ---- prefetch next tile's K/V into fresh regs ----
    const u16* kpn = kgb + (size_t)kbn*64;
    const u16* vpn = vgb + kbn;
    bf16x8 nk0 = *(const bf16x8*)(kpn +  0);
    bf16x8 nk1 = *(const bf16x8*)(kpn + 16);
    bf16x8 nk2 = *(const bf16x8*)(kpn + 32);
    bf16x8 nk3 = *(const bf16x8*)(kpn + 48);
    bf16x8 nv00 = *(const bf16x8*)(vpn + 0);
    bf16x8 nv01 = *(const bf16x8*)(vpn + 16);
    bf16x8 nv10 = *(const bf16x8*)(vpn + 32*2048 + 0);
    bf16x8 nv11 = *(const bf16x8*)(vpn + 32*2048 + 16);

    // ---- S^T = K * Q^T over d=64 (4 mfma) ----
    f32x16 c = {};
    c = mfma32(k0, qf0, c);
    c = mfma32(k1, qf1, c);
    c = mfma32(k2, qf2, c);
    c = mfma32(k3, qf3, c);

    // ---- scale + mask + in-lane softmax ----
    // lane's key for reg r: kb + (r&3) + 8*(r>>2) + 4*hi
    const bool diag = (kb == q0);                 // only diagonal tile masks
    float p0,p1,p2,p3,p4,p5,p6,p7,p8,p9,p10,p11,p12,p13,p14,p15;
    {
      float mx = -3.0e38f;
      #define SMASK(r, P) { \
        const int key = kb + ((r)&3) + 8*((r)>>2) + 4*hi; \
        float v = c[r] * 0.125f; \
        if (diag && key > q) v = -3.0e38f; \
        P = v; mx = fmaxf(mx, v); }
      SMASK(0,p0) SMASK(1,p1) SMASK(2,p2) SMASK(3,p3)
      SMASK(4,p4) SMASK(5,p5) SMASK(6,p6) SMASK(7,p7)
      SMASK(8,p8) SMASK(9,p9) SMASK(10,p10) SMASK(11,p11)
      SMASK(12,p12) SMASK(13,p13) SMASK(14,p14) SMASK(15,p15)
      #undef SMASK
      mx = fmaxf(mx, __shfl_xor(mx, 32));
      const float mn = fmaxf(m, mx);
      const float scale = __expf(m - mn);
      m = mn;
      float rs = 0.f;
      #define SEXP(P) { P = __expf(P - mn); rs += P; }
      SEXP(p0) SEXP(p1) SEXP(p2) SEXP(p3) SEXP(p4) SEXP(p5) SEXP(p6) SEXP(p7)
      SEXP(p8) SEXP(p9) SEXP(p10) SEXP(p11) SEXP(p12) SEXP(p13) SEXP(p14) SEXP(p15)
      #undef SEXP
      rs += __shfl_xor(rs, 32);
      l = l * scale + rs;
      #pragma unroll
      for (int r = 0; r < 16; ++r){ oc0[r] *= scale; oc1[r] *= scale; }
    }

    // ---- P^T -> bf16 words + half-exchange -> PV B-fragments ----
    const unsigned w0 = packbf(p0,p1),   w1 = packbf(p2,p3);
    const unsigned w2 = packbf(p4,p5),   w3 = packbf(p6,p7);
    const unsigned w4 = packbf(p8,p9),   w5 = packbf(p10,p11);
    const unsigned w6 = packbf(p12,p13), w7 = packbf(p14,p15);
    const unsigned x0 = __shfl_xor(w0, 32), x1 = __shfl_xor(w1, 32);
    const unsigned x2 = __shfl_xor(w2, 32), x3 = __shfl_xor(w3, 32);
    const unsigned x4 = __shfl_xor(w4, 32), x5 = __shfl_xor(w5, 32);
    const unsigned x6 = __shfl_xor(w6, 32), x7 = __shfl_xor(w7, 32);
    // kt=0 needs keys (hi?8:0)+0..7 ; kt=1 needs keys 16+(hi?8:0)+0..7
    u32x4 pa = { hi ? x2 : w0, hi ? x3 : w1, hi ? w2 : x0, hi ? w3 : x1 };
    u32x4 pb = { hi ? x6 : w4, hi ? x7 : w5, hi ? w6 : x4, hi ? w7 : x5 };
    const bf16x8 pf0 = __builtin_bit_cast(bf16x8, pa);
    const bf16x8 pf1 = __builtin_bit_cast(bf16x8, pb);

    // ---- O^T += V^T * P^T (4 mfma) ----
    oc0 = mfma32(v00, pf0, oc0);
    oc0 = mfma32(v01, pf1, oc0);
    oc1 = mfma32(v10, pf0, oc1);
    oc1 = mfma32(v11, pf1, oc1);

    // ---- rotate prefetched regs in ----
    k0 = nk0; k1 = nk1; k2 = nk2; k3 = nk3;
    v00 = nv00; v01 = nv01; v10 = nv10; v11 = nv11;
  }

  // ---- normalize + write O (lane owns column q; reg r -> d) ----
  const float inv = 1.0f / l;
  u16* aop = ao + (size_t)q*1024 + h*64;
  #pragma unroll
  for (int rq = 0; rq < 4; ++rq){
    ushort4 pk;
    pk.x = f2bf(oc0[rq*4+0]*inv); pk.y = f2bf(oc0[rq*4+1]*inv);
    pk.z = f2bf(oc0[rq*4+2]*inv); pk.w = f2bf(oc0[rq*4+3]*inv);
    *(ushort4*)(aop + 8*rq + 4*hi) = pk;
    pk.x = f2bf(oc1[rq*4+0]*inv); pk.y = f2bf(oc1[rq*4+1]*inv);
    pk.z = f2bf(oc1[rq*4+2]*inv); pk.w = f2bf(oc1[rq*4+3]*inv);
    *(ushort4*)(aop + 32 + 8*rq + 4*hi) = pk;
  }
}

// ---------- launch ----------
extern "C" void kernel_launch(void* const* d_in, const int* in_sizes, int n_in,
                              void* d_out, int out_size, void* d_ws, size_t ws_size,
                              hipStream_t stream) {
  const float* x  = (const float*)d_in[0];   // (1,2048,1024)
  const float* wq = (const float*)d_in[1];   // (3072,1024)
  const float* wo = (const float*)d_in[2];   // (1024,1024)
  float* out = (float*)d_out;                // (1,2048,1024) fp32

  char* w = (char*)d_ws;                     // 44 MB used
  u16*   xb  = (u16*)(w + (size_t) 0);        // 4 MB  x bf16
  u16*   wqb = (u16*)(w + (size_t)( 4<<20));  // 6 MB  Wqkv bf16
  u16*   wob = (u16*)(w + (size_t)(10<<20));  // 2 MB  Wout bf16
  u16*   q_r = (u16*)(w + (size_t)(12<<20));  // 4 MB  q roped bf16 [16][2048][64]
  u16*   k_r = (u16*)(w + (size_t)(16<<20));  // 4 MB  k roped bf16 [16][2048][64]
  u16*   v_t = (u16*)(w + (size_t)(20<<20));  // 4 MB  v bf16 transposed [16][64][2048]
  u16*   ao  = (u16*)(w + (size_t)(24<<20));  // 4 MB  attn out bf16 [2048][1024]
  float* qkf = (float*)(w + (size_t)(28<<20)); // 16 MB q,k fp32 [2][16][2048][64]

  convert_kernel<<<2048, 256, 0, stream>>>(x, wq, wo, xb, wqb, wob);
  gemm_bt<1><<<dim3(24, 16), 512, 0, stream>>>(xb, wqb, 1024, nullptr, 0, v_t, qkf);
  rope_kernel<<<8192, 256, 0, stream>>>(qkf, q_r, k_r);
  attn_kernel<<<1024, 64, 0, stream>>>(q_r, k_r, v_t, ao);
  gemm_bt<0><<<dim3(8, 16), 512, 0, stream>>>(ao, wob, 1024, out, 1024, nullptr, nullptr);
}